// Round 12
// baseline (248.422 us; speedup 1.0000x reference)
//
#include <hip/hip_runtime.h>

#define N_NODES_C 100000
#define N_EDGES_C 1600000
#define NCHUNK 256                 // hist chunks
#define CHH (N_EDGES_C / NCHUNK)   // 6250
#define NPART 128                  // partition blocks (2 chunks each)
#define CHP (N_EDGES_C / NPART)    // 12500
#define BUCK_SH 7
#define BUCK_NODES 128
#define NB_BUCK 782                // ceil(100000 / 128)

typedef short short8 __attribute__((ext_vector_type(8)));
typedef float f32x4 __attribute__((ext_vector_type(4)));

// float -> bf16 bits (RNE)
__device__ __forceinline__ short f2bf(float f) {
  unsigned u = __builtin_bit_cast(unsigned, f);
  unsigned r = (u + 0x7FFFu + ((u >> 16) & 1u)) >> 16;
  return (short)r;
}

// fp8 e4m3 (OCP): manual encode (RNE, FTZ below 2^-6) / decode.
__device__ __forceinline__ float fp8_to_f32(unsigned b) {
  unsigned f = ((b & 0x80u) << 24) | (((b & 0x7Fu) + 0x3C0u) << 20);
  return (b & 0x78u) ? __builtin_bit_cast(float, f) : 0.f;
}
__device__ __forceinline__ unsigned f32_to_fp8(float x) {
  unsigned u = __builtin_bit_cast(unsigned, x);
  unsigned s = (u >> 24) & 0x80u;
  unsigned au = u & 0x7FFFFFFFu;
  if (au < (121u << 23)) return s;  // flush to +/-0
  unsigned r = au + 0x7FFFFu + ((au >> 20) & 1u);
  unsigned e8 = (r >> 23) - 120u;
  unsigned m = (r >> 20) & 7u;
  if (e8 > 15u) { e8 = 15u; m = 6u; }  // clamp to 448
  return s | (e8 << 3) | m;
}

// ---------------------------------------------------------------------------
// MFMA GEMM body: out[n][64] = in[n][K] @ W[K][64], fp32 in, fp8 out.
// 4 waves/block, each wave a 16x64 tile via 4 n-tiles of mfma 16x16x32_bf16.
// ---------------------------------------------------------------------------
template <int K>
__device__ __forceinline__ void gemm64_body(
    int gblock, const float* __restrict__ in_, const float* __restrict__ W,
    unsigned char* __restrict__ out_, int n_rows) {
  constexpr int KS = K / 32;
  int wave = threadIdx.x >> 6;
  int lane = threadIdx.x & 63;
  int row0 = (gblock * 4 + wave) * 16;
  if (row0 >= n_rows) return;

  int lrow = lane & 15;
  int lk = (lane >> 4) * 8;

  short8 bfrag[KS][4];
#pragma unroll
  for (int ks = 0; ks < KS; ++ks)
#pragma unroll
    for (int nt = 0; nt < 4; ++nt) {
      short8 b;
#pragma unroll
      for (int j = 0; j < 8; ++j)
        b[j] = f2bf(W[(size_t)(ks * 32 + lk + j) * 64 + nt * 16 + lrow]);
      bfrag[ks][nt] = b;
    }

  int row = row0 + lrow;
  f32x4 acc[4] = {};
#pragma unroll
  for (int ks = 0; ks < KS; ++ks) {
    short8 a;
    const float* ip = in_ + (size_t)row * K + ks * 32 + lk;
    f32x4 v0 = *(const f32x4*)(ip);
    f32x4 v1 = *(const f32x4*)(ip + 4);
#pragma unroll
    for (int j = 0; j < 4; ++j) {
      a[j] = f2bf(v0[j]);
      a[4 + j] = f2bf(v1[j]);
    }
#pragma unroll
    for (int nt = 0; nt < 4; ++nt)
      acc[nt] = __builtin_amdgcn_mfma_f32_16x16x32_bf16(a, bfrag[ks][nt],
                                                        acc[nt], 0, 0, 0);
  }

  int crow = row0 + (lane >> 4) * 4;
#pragma unroll
  for (int nt = 0; nt < 4; ++nt) {
    int ocol = nt * 16 + lrow;
#pragma unroll
    for (int r = 0; r < 4; ++r)
      out_[(size_t)(crow + r) * 64 + ocol] = (unsigned char)f32_to_fp8(acc[nt][r]);
  }
}

// ---------------------------------------------------------------------------
// Bucket histogram over 256 chunks (LDS int atomics) -> countsT[bucket][chunk]
// ---------------------------------------------------------------------------
__global__ __launch_bounds__(256) void hist_kernel(
    const int* __restrict__ dst, int* __restrict__ countsT) {
  __shared__ int lhist[NB_BUCK];
  int cb = (int)blockIdx.x;
  for (int i = threadIdx.x; i < NB_BUCK; i += 256) lhist[i] = 0;
  __syncthreads();
  int beg = cb * CHH, end = beg + CHH;
  for (int i = beg + (int)threadIdx.x; i < end; i += 256)
    atomicAdd(&lhist[((unsigned)dst[i]) >> BUCK_SH], 1);
  __syncthreads();
  for (int bb = threadIdx.x; bb < NB_BUCK; bb += 256)
    countsT[bb * NCHUNK + cb] = lhist[bb];
}

// K1: per-bucket exclusive scan over NCHUNK=256 chunk counts (+ total).
__global__ __launch_bounds__(256) void scan_buckets_kernel(
    int* __restrict__ countsT, int* __restrict__ btot) {
  int b = blockIdx.x * 4 + (threadIdx.x >> 6);
  int lane = threadIdx.x & 63;
  if (b >= NB_BUCK) return;
  int4 v = *(const int4*)(countsT + b * NCHUNK + lane * 4);
  int s = v.x + v.y + v.z + v.w;
  int incl = s;
#pragma unroll
  for (int d = 1; d < 64; d <<= 1) {
    int t = __shfl_up(incl, d, 64);
    if (lane >= d) incl += t;
  }
  int excl = incl - s;
  int4 o;
  o.x = excl;
  o.y = excl + v.x;
  o.z = o.y + v.y;
  o.w = o.z + v.z;
  *(int4*)(countsT + b * NCHUNK + lane * 4) = o;
  if (lane == 63) btot[b] = incl;
}

// K2: exclusive scan of bucket totals -> bstart[0..NB_BUCK].
__global__ __launch_bounds__(1024) void scan_btot_kernel(
    const int* __restrict__ btot, int* __restrict__ bstart) {
  __shared__ int lds[1024];
  int t = threadIdx.x;
  int v = (t < NB_BUCK) ? btot[t] : 0;
  lds[t] = v;
  __syncthreads();
  for (int off = 1; off < 1024; off <<= 1) {
    int tv = (t >= off) ? lds[t - off] : 0;
    __syncthreads();
    lds[t] += tv;
    __syncthreads();
  }
  if (t < NB_BUCK) bstart[t] = lds[t] - v;
  if (t == NB_BUCK - 1) bstart[NB_BUCK] = lds[t];
}

// ---------------------------------------------------------------------------
// Fused: blocks [0,NPART) = partition (2 chunks each; 64B runs);
// blocks [NPART, +gemm_grid) = GEMM1 (x@W1 -> hA fp8). Independent.
// ---------------------------------------------------------------------------
__global__ __launch_bounds__(256) void part_gemm1_kernel(
    const int* __restrict__ src, const int* __restrict__ dst,
    const int* __restrict__ offs /* countsT after K1 */,
    const int* __restrict__ bstart, unsigned* __restrict__ packed,
    const float* __restrict__ x, const float* __restrict__ W1,
    unsigned char* __restrict__ hA, int n_rows) {
  __shared__ int cur[NB_BUCK];
  int b = (int)blockIdx.x;
  if (b >= NPART) {
    gemm64_body<128>(b - NPART, x, W1, hA, n_rows);
    return;
  }
  for (int bb = threadIdx.x; bb < NB_BUCK; bb += 256)
    cur[bb] = bstart[bb] + offs[bb * NCHUNK + 2 * b];
  __syncthreads();
  int beg = b * CHP, end = beg + CHP;
  for (int i = beg + (int)threadIdx.x; i < end; i += 256) {
    int d = dst[i];
    int s = src[i];
    int bb = ((unsigned)d) >> BUCK_SH;
    int pos = atomicAdd(&cur[bb], 1);
    packed[pos] = ((unsigned)(d & (BUCK_NODES - 1)) << 17) | (unsigned)s;
  }
}

// ---------------------------------------------------------------------------
// Per-bucket counting sort -> dst-sorted col[] + row_ptr[] (global CSR).
// ---------------------------------------------------------------------------
__global__ __launch_bounds__(256) void sort_bucket_kernel(
    const unsigned* __restrict__ packed, const int* __restrict__ bstart,
    int* __restrict__ col, int* __restrict__ row_ptr, int n_nodes,
    int n_edges) {
  __shared__ int lhist[BUCK_NODES];
  __shared__ int lcur[BUCK_NODES];
  __shared__ int wsum0;
  int b = (int)blockIdx.x;
  int beg = bstart[b], end = bstart[b + 1];
  int t = (int)threadIdx.x;

  if (t < BUCK_NODES) lhist[t] = 0;
  __syncthreads();
  for (int e = beg + t; e < end; e += 256)
    atomicAdd(&lhist[packed[e] >> 17], 1);
  __syncthreads();

  int v = 0, incl = 0;
  if (t < BUCK_NODES) {
    v = lhist[t];
    incl = v;
#pragma unroll
    for (int d = 1; d < 64; d <<= 1) {
      int u = __shfl_up(incl, d, 64);
      if ((t & 63) >= d) incl += u;
    }
  }
  if (t == 63) wsum0 = incl;
  __syncthreads();
  if (t >= 64 && t < BUCK_NODES) incl += wsum0;
  if (t < BUCK_NODES) {
    int excl = incl - v;
    lcur[t] = excl;
    int node = b * BUCK_NODES + t;
    if (node < n_nodes) row_ptr[node] = beg + excl;
  }
  if (b == NB_BUCK - 1 && t == 0) row_ptr[n_nodes] = n_edges;
  __syncthreads();

  for (int e = beg + t; e < end; e += 256) {
    unsigned pe = packed[e];
    int ld = (int)(pe >> 17);
    int pos = beg + atomicAdd(&lcur[ld], 1);
    col[pos] = (int)(pe & 0x1FFFFu);
  }
}

// ---------------------------------------------------------------------------
// Agg inner (fp8 table): one node's sorted edge range. h row = 64B = 1 line.
// lane = (edge slot 0..3) x (channel quad 0..15); lane loads uint (4 fp8 ch).
// ---------------------------------------------------------------------------
__device__ __forceinline__ void agg_node(
    const unsigned char* __restrict__ h, const int* __restrict__ col, int beg,
    int end, int slot, int q, float& s0, float& s1, float& s2, float& s3) {
  s0 = s1 = s2 = s3 = 0.f;
  float t0 = 0.f, t1 = 0.f, t2 = 0.f, t3 = 0.f;
  int e = beg + slot;
  for (; e + 12 < end; e += 16) {
    int sa = col[e];
    int sb = col[e + 4];
    int sc = col[e + 8];
    int sd = col[e + 12];
    unsigned ua = *(const unsigned*)(h + (size_t)sa * 64 + q * 4);
    unsigned ub = *(const unsigned*)(h + (size_t)sb * 64 + q * 4);
    unsigned uc = *(const unsigned*)(h + (size_t)sc * 64 + q * 4);
    unsigned ud = *(const unsigned*)(h + (size_t)sd * 64 + q * 4);
    s0 += fp8_to_f32(ua & 255u) + fp8_to_f32(ub & 255u);
    s1 += fp8_to_f32((ua >> 8) & 255u) + fp8_to_f32((ub >> 8) & 255u);
    s2 += fp8_to_f32((ua >> 16) & 255u) + fp8_to_f32((ub >> 16) & 255u);
    s3 += fp8_to_f32(ua >> 24) + fp8_to_f32(ub >> 24);
    t0 += fp8_to_f32(uc & 255u) + fp8_to_f32(ud & 255u);
    t1 += fp8_to_f32((uc >> 8) & 255u) + fp8_to_f32((ud >> 8) & 255u);
    t2 += fp8_to_f32((uc >> 16) & 255u) + fp8_to_f32((ud >> 16) & 255u);
    t3 += fp8_to_f32(uc >> 24) + fp8_to_f32(ud >> 24);
  }
  for (; e < end; e += 4) {
    int sa = col[e];
    unsigned ua = *(const unsigned*)(h + (size_t)sa * 64 + q * 4);
    s0 += fp8_to_f32(ua & 255u);
    s1 += fp8_to_f32((ua >> 8) & 255u);
    s2 += fp8_to_f32((ua >> 16) & 255u);
    s3 += fp8_to_f32(ua >> 24);
  }
  s0 += t0;
  s1 += t1;
  s2 += t2;
  s3 += t3;
  s0 += __shfl_xor(s0, 16);
  s1 += __shfl_xor(s1, 16);
  s2 += __shfl_xor(s2, 16);
  s3 += __shfl_xor(s3, 16);
  s0 += __shfl_xor(s0, 32);
  s1 += __shfl_xor(s1, 32);
  s2 += __shfl_xor(s2, 32);
  s3 += __shfl_xor(s3, 32);
}

// ---------------------------------------------------------------------------
// Fused agg + bias + ReLU + (row @ W) -> fp8. Block = 16 nodes, 4 waves.
// ---------------------------------------------------------------------------
__global__ __launch_bounds__(256) void agg_gemm_kernel(
    const unsigned char* __restrict__ h, const int* __restrict__ row_ptr,
    const int* __restrict__ col, const float* __restrict__ bias,
    const float* __restrict__ W, unsigned char* __restrict__ outg,
    int n_nodes) {
  __shared__ float rowbuf[16][68];
  int wid = threadIdx.x >> 6;
  int lane = threadIdx.x & 63;
  int slot = lane >> 4;
  int q = lane & 15;
  int nbase = blockIdx.x * 16;

#pragma unroll
  for (int n = 0; n < 4; ++n) {
    int ln = wid * 4 + n;
    int node = nbase + ln;
    float s0, s1, s2, s3;
    agg_node(h, col, row_ptr[node], row_ptr[node + 1], slot, q, s0, s1, s2, s3);
    if (lane < 16) {
      f32x4 r;
      r[0] = fmaxf(s0 + bias[q * 4 + 0], 0.f);
      r[1] = fmaxf(s1 + bias[q * 4 + 1], 0.f);
      r[2] = fmaxf(s2 + bias[q * 4 + 2], 0.f);
      r[3] = fmaxf(s3 + bias[q * 4 + 3], 0.f);
      *(f32x4*)&rowbuf[ln][q * 4] = r;
    }
  }
  __syncthreads();

  int lrow = lane & 15;
  int lk = (lane >> 4) * 8;
  f32x4 acc = {};
#pragma unroll
  for (int ks = 0; ks < 2; ++ks) {
    short8 a, bv;
#pragma unroll
    for (int j = 0; j < 8; ++j) a[j] = f2bf(rowbuf[lrow][ks * 32 + lk + j]);
#pragma unroll
    for (int j = 0; j < 8; ++j)
      bv[j] = f2bf(W[(size_t)(ks * 32 + lk + j) * 64 + wid * 16 + lrow]);
    acc = __builtin_amdgcn_mfma_f32_16x16x32_bf16(a, bv, acc, 0, 0, 0);
  }
  int crow = (lane >> 4) * 4;
#pragma unroll
  for (int r = 0; r < 4; ++r)
    outg[(size_t)(nbase + crow + r) * 64 + wid * 16 + lrow] =
        (unsigned char)f32_to_fp8(acc[r]);
}

// ---------------------------------------------------------------------------
// Final agg + bias + ReLU (fp32 out). Wave per node.
// ---------------------------------------------------------------------------
__global__ __launch_bounds__(256) void agg_final_kernel(
    const unsigned char* __restrict__ h, const int* __restrict__ row_ptr,
    const int* __restrict__ col, const float* __restrict__ bias,
    float* __restrict__ out, int n_nodes) {
  int node = blockIdx.x * 4 + (threadIdx.x >> 6);
  if (node >= n_nodes) return;
  int lane = threadIdx.x & 63;
  int slot = lane >> 4;
  int q = lane & 15;
  float s0, s1, s2, s3;
  agg_node(h, col, row_ptr[node], row_ptr[node + 1], slot, q, s0, s1, s2, s3);
  if (lane < 16) {
    float4 v;
    v.x = fmaxf(s0 + bias[q * 4 + 0], 0.f);
    v.y = fmaxf(s1 + bias[q * 4 + 1], 0.f);
    v.z = fmaxf(s2 + bias[q * 4 + 2], 0.f);
    v.w = fmaxf(s3 + bias[q * 4 + 3], 0.f);
    ((float4*)out)[(size_t)node * 16 + q] = v;
  }
}

extern "C" void kernel_launch(void* const* d_in, const int* in_sizes, int n_in,
                              void* d_out, int out_size, void* d_ws,
                              size_t ws_size, hipStream_t stream) {
  const float* x = (const float*)d_in[0];
  const int* src = (const int*)d_in[1];
  const int* dst = (const int*)d_in[2];
  const float* W1 = (const float*)d_in[3];
  const float* b1 = (const float*)d_in[4];
  const float* W2 = (const float*)d_in[5];
  const float* b2 = (const float*)d_in[6];
  const float* W3 = (const float*)d_in[7];
  const float* b3 = (const float*)d_in[8];
  float* out = (float*)d_out;

  const int N = N_NODES_C;
  const int E = N_EDGES_C;

  // Workspace layout (31 MB):
  //   [0, 1MB)     countsT[NB_BUCK][NCHUNK] (800 KB; becomes offs after K1)
  //   [1MB, +4KB)  btot ; [1MB+16KB) bstart
  //   [2, 3MB)     row_ptr (N+1)
  //   [3, 10MB)    packed edges (E u32)
  //   [10, 17MB)   col (E int, dst-sorted src)
  //   [17, 24MB)   hA (N*64 fp8 = 6.4MB) ; [24, 31MB) hB
  char* ws = (char*)d_ws;
  int* countsT = (int*)(ws + 0);
  int* btot = (int*)(ws + (1u << 20));
  int* bstart = (int*)(ws + (1u << 20) + (16u << 10));
  int* row_ptr = (int*)(ws + (2u << 20));
  unsigned* packed = (unsigned*)(ws + (3u << 20));
  int* col = (int*)(ws + (10u << 20));
  unsigned char* hA = (unsigned char*)(ws + (17u << 20));
  unsigned char* hB = (unsigned char*)(ws + (24u << 20));

  const int gemm_grid = (N + 63) / 64;  // 1563
  const int k1_grid = (NB_BUCK + 3) / 4;
  const int aggg_grid = N / 16;         // 6250
  const int aggf_grid = (N + 3) / 4;    // 25000

  // ---- CSR build; gemm1 overlapped with partition ----
  hist_kernel<<<NCHUNK, 256, 0, stream>>>(dst, countsT);
  scan_buckets_kernel<<<k1_grid, 256, 0, stream>>>(countsT, btot);
  scan_btot_kernel<<<1, 1024, 0, stream>>>(btot, bstart);
  part_gemm1_kernel<<<NPART + gemm_grid, 256, 0, stream>>>(
      src, dst, countsT, bstart, packed, x, W1, hA, N);
  sort_bucket_kernel<<<NB_BUCK, 256, 0, stream>>>(packed, bstart, col, row_ptr,
                                                  N, E);

  // ---- Layer 1 agg fused with gemm2: hB = fp8(relu(agg(hA)+b1) @ W2) ----
  agg_gemm_kernel<<<aggg_grid, 256, 0, stream>>>(hA, row_ptr, col, b1, W2, hB,
                                                 N);
  // ---- Layer 2 agg fused with gemm3: hA = fp8(relu(agg(hB)+b2) @ W3) ----
  agg_gemm_kernel<<<aggg_grid, 256, 0, stream>>>(hB, row_ptr, col, b2, W3, hA,
                                                 N);
  // ---- Layer 3 final: out = relu(agg(hA)+b3) (fp32) ----
  agg_final_kernel<<<aggf_grid, 256, 0, stream>>>(hA, row_ptr, col, b3, out, N);
}

// Round 13
// 209.342 us; speedup vs baseline: 1.1867x; 1.1867x over previous
//
#include <hip/hip_runtime.h>

#define N_NODES_C 100000
#define N_EDGES_C 1600000
#define NCHUNK 256                 // hist chunks
#define CHH (N_EDGES_C / NCHUNK)   // 6250
#define NPART 128                  // partition blocks (2 chunks each)
#define CHP (N_EDGES_C / NPART)    // 12500
#define BUCK_SH 7
#define BUCK_NODES 128
#define NB_BUCK 782                // ceil(100000 / 128)

typedef short short8 __attribute__((ext_vector_type(8)));
typedef float f32x4 __attribute__((ext_vector_type(4)));
typedef float f32x2 __attribute__((ext_vector_type(2)));

// float -> bf16 bits (RNE)
__device__ __forceinline__ short f2bf(float f) {
  unsigned u = __builtin_bit_cast(unsigned, f);
  unsigned r = (u + 0x7FFFu + ((u >> 16) & 1u)) >> 16;
  return (short)r;
}

// HW fp8 (OCP e4m3 on gfx950) conversions.
__device__ __forceinline__ unsigned char f32_to_fp8_hw(float x) {
  return (unsigned char)(__builtin_amdgcn_cvt_pk_fp8_f32(x, x, 0, false) & 0xFF);
}

// ---------------------------------------------------------------------------
// MFMA GEMM body: out[n][64] = in[n][K] @ W[K][64], fp32 in, fp8 out.
// ---------------------------------------------------------------------------
template <int K>
__device__ __forceinline__ void gemm64_body(
    int gblock, const float* __restrict__ in_, const float* __restrict__ W,
    unsigned char* __restrict__ out_, int n_rows) {
  constexpr int KS = K / 32;
  int wave = threadIdx.x >> 6;
  int lane = threadIdx.x & 63;
  int row0 = (gblock * 4 + wave) * 16;
  if (row0 >= n_rows) return;

  int lrow = lane & 15;
  int lk = (lane >> 4) * 8;

  short8 bfrag[KS][4];
#pragma unroll
  for (int ks = 0; ks < KS; ++ks)
#pragma unroll
    for (int nt = 0; nt < 4; ++nt) {
      short8 b;
#pragma unroll
      for (int j = 0; j < 8; ++j)
        b[j] = f2bf(W[(size_t)(ks * 32 + lk + j) * 64 + nt * 16 + lrow]);
      bfrag[ks][nt] = b;
    }

  int row = row0 + lrow;
  f32x4 acc[4] = {};
#pragma unroll
  for (int ks = 0; ks < KS; ++ks) {
    short8 a;
    const float* ip = in_ + (size_t)row * K + ks * 32 + lk;
    f32x4 v0 = *(const f32x4*)(ip);
    f32x4 v1 = *(const f32x4*)(ip + 4);
#pragma unroll
    for (int j = 0; j < 4; ++j) {
      a[j] = f2bf(v0[j]);
      a[4 + j] = f2bf(v1[j]);
    }
#pragma unroll
    for (int nt = 0; nt < 4; ++nt)
      acc[nt] = __builtin_amdgcn_mfma_f32_16x16x32_bf16(a, bfrag[ks][nt],
                                                        acc[nt], 0, 0, 0);
  }

  int crow = row0 + (lane >> 4) * 4;
#pragma unroll
  for (int nt = 0; nt < 4; ++nt) {
    int ocol = nt * 16 + lrow;
#pragma unroll
    for (int r = 0; r < 4; ++r)
      out_[(size_t)(crow + r) * 64 + ocol] = f32_to_fp8_hw(acc[nt][r]);
  }
}

// ---------------------------------------------------------------------------
// Bucket histogram over 256 chunks (LDS int atomics) -> countsT[bucket][chunk]
// ---------------------------------------------------------------------------
__global__ __launch_bounds__(256) void hist_kernel(
    const int* __restrict__ dst, int* __restrict__ countsT) {
  __shared__ int lhist[NB_BUCK];
  int cb = (int)blockIdx.x;
  for (int i = threadIdx.x; i < NB_BUCK; i += 256) lhist[i] = 0;
  __syncthreads();
  int beg = cb * CHH, end = beg + CHH;
  for (int i = beg + (int)threadIdx.x; i < end; i += 256)
    atomicAdd(&lhist[((unsigned)dst[i]) >> BUCK_SH], 1);
  __syncthreads();
  for (int bb = threadIdx.x; bb < NB_BUCK; bb += 256)
    countsT[bb * NCHUNK + cb] = lhist[bb];
}

// K1: per-bucket exclusive scan over NCHUNK=256 chunk counts (+ total).
__global__ __launch_bounds__(256) void scan_buckets_kernel(
    int* __restrict__ countsT, int* __restrict__ btot) {
  int b = blockIdx.x * 4 + (threadIdx.x >> 6);
  int lane = threadIdx.x & 63;
  if (b >= NB_BUCK) return;
  int4 v = *(const int4*)(countsT + b * NCHUNK + lane * 4);
  int s = v.x + v.y + v.z + v.w;
  int incl = s;
#pragma unroll
  for (int d = 1; d < 64; d <<= 1) {
    int t = __shfl_up(incl, d, 64);
    if (lane >= d) incl += t;
  }
  int excl = incl - s;
  int4 o;
  o.x = excl;
  o.y = excl + v.x;
  o.z = o.y + v.y;
  o.w = o.z + v.z;
  *(int4*)(countsT + b * NCHUNK + lane * 4) = o;
  if (lane == 63) btot[b] = incl;
}

// K2: exclusive scan of bucket totals -> bstart[0..NB_BUCK].
__global__ __launch_bounds__(1024) void scan_btot_kernel(
    const int* __restrict__ btot, int* __restrict__ bstart) {
  __shared__ int lds[1024];
  int t = threadIdx.x;
  int v = (t < NB_BUCK) ? btot[t] : 0;
  lds[t] = v;
  __syncthreads();
  for (int off = 1; off < 1024; off <<= 1) {
    int tv = (t >= off) ? lds[t - off] : 0;
    __syncthreads();
    lds[t] += tv;
    __syncthreads();
  }
  if (t < NB_BUCK) bstart[t] = lds[t] - v;
  if (t == NB_BUCK - 1) bstart[NB_BUCK] = lds[t];
}

// ---------------------------------------------------------------------------
// Fused: blocks [0,NPART) = partition (64B runs); rest = GEMM1 (x@W1 -> fp8).
// ---------------------------------------------------------------------------
__global__ __launch_bounds__(256) void part_gemm1_kernel(
    const int* __restrict__ src, const int* __restrict__ dst,
    const int* __restrict__ offs /* countsT after K1 */,
    const int* __restrict__ bstart, unsigned* __restrict__ packed,
    const float* __restrict__ x, const float* __restrict__ W1,
    unsigned char* __restrict__ hA, int n_rows) {
  __shared__ int cur[NB_BUCK];
  int b = (int)blockIdx.x;
  if (b >= NPART) {
    gemm64_body<128>(b - NPART, x, W1, hA, n_rows);
    return;
  }
  for (int bb = threadIdx.x; bb < NB_BUCK; bb += 256)
    cur[bb] = bstart[bb] + offs[bb * NCHUNK + 2 * b];
  __syncthreads();
  int beg = b * CHP, end = beg + CHP;
  for (int i = beg + (int)threadIdx.x; i < end; i += 256) {
    int d = dst[i];
    int s = src[i];
    int bb = ((unsigned)d) >> BUCK_SH;
    int pos = atomicAdd(&cur[bb], 1);
    packed[pos] = ((unsigned)(d & (BUCK_NODES - 1)) << 17) | (unsigned)s;
  }
}

// ---------------------------------------------------------------------------
// Per-bucket counting sort -> dst-sorted col[] + row_ptr[] (global CSR).
// ---------------------------------------------------------------------------
__global__ __launch_bounds__(256) void sort_bucket_kernel(
    const unsigned* __restrict__ packed, const int* __restrict__ bstart,
    int* __restrict__ col, int* __restrict__ row_ptr, int n_nodes,
    int n_edges) {
  __shared__ int lhist[BUCK_NODES];
  __shared__ int lcur[BUCK_NODES];
  __shared__ int wsum0;
  int b = (int)blockIdx.x;
  int beg = bstart[b], end = bstart[b + 1];
  int t = (int)threadIdx.x;

  if (t < BUCK_NODES) lhist[t] = 0;
  __syncthreads();
  for (int e = beg + t; e < end; e += 256)
    atomicAdd(&lhist[packed[e] >> 17], 1);
  __syncthreads();

  int v = 0, incl = 0;
  if (t < BUCK_NODES) {
    v = lhist[t];
    incl = v;
#pragma unroll
    for (int d = 1; d < 64; d <<= 1) {
      int u = __shfl_up(incl, d, 64);
      if ((t & 63) >= d) incl += u;
    }
  }
  if (t == 63) wsum0 = incl;
  __syncthreads();
  if (t >= 64 && t < BUCK_NODES) incl += wsum0;
  if (t < BUCK_NODES) {
    int excl = incl - v;
    lcur[t] = excl;
    int node = b * BUCK_NODES + t;
    if (node < n_nodes) row_ptr[node] = beg + excl;
  }
  if (b == NB_BUCK - 1 && t == 0) row_ptr[n_nodes] = n_edges;
  __syncthreads();

  for (int e = beg + t; e < end; e += 256) {
    unsigned pe = packed[e];
    int ld = (int)(pe >> 17);
    int pos = beg + atomicAdd(&lcur[ld], 1);
    col[pos] = (int)(pe & 0x1FFFFu);
  }
}

// ---------------------------------------------------------------------------
// Agg inner (fp8 table, HW decode): one node's sorted edge range.
// lane = (edge slot 0..3) x (channel quad 0..15); lane loads uint (4 fp8 ch);
// decode = 2x v_cvt_pk_f32_fp8 per word.
// ---------------------------------------------------------------------------
__device__ __forceinline__ void agg_node(
    const unsigned char* __restrict__ h, const int* __restrict__ col, int beg,
    int end, int slot, int q, float& s0, float& s1, float& s2, float& s3) {
  s0 = s1 = s2 = s3 = 0.f;
  float t0 = 0.f, t1 = 0.f, t2 = 0.f, t3 = 0.f;
  int e = beg + slot;
  for (; e + 12 < end; e += 16) {
    int sa = col[e];
    int sb = col[e + 4];
    int sc = col[e + 8];
    int sd = col[e + 12];
    int ua = *(const int*)(h + (size_t)sa * 64 + q * 4);
    int ub = *(const int*)(h + (size_t)sb * 64 + q * 4);
    int uc = *(const int*)(h + (size_t)sc * 64 + q * 4);
    int ud = *(const int*)(h + (size_t)sd * 64 + q * 4);
    f32x2 al = __builtin_amdgcn_cvt_pk_f32_fp8(ua, false);
    f32x2 ah = __builtin_amdgcn_cvt_pk_f32_fp8(ua, true);
    f32x2 bl = __builtin_amdgcn_cvt_pk_f32_fp8(ub, false);
    f32x2 bh = __builtin_amdgcn_cvt_pk_f32_fp8(ub, true);
    f32x2 cl = __builtin_amdgcn_cvt_pk_f32_fp8(uc, false);
    f32x2 ch = __builtin_amdgcn_cvt_pk_f32_fp8(uc, true);
    f32x2 dl = __builtin_amdgcn_cvt_pk_f32_fp8(ud, false);
    f32x2 dh = __builtin_amdgcn_cvt_pk_f32_fp8(ud, true);
    s0 += al[0] + bl[0];
    s1 += al[1] + bl[1];
    s2 += ah[0] + bh[0];
    s3 += ah[1] + bh[1];
    t0 += cl[0] + dl[0];
    t1 += cl[1] + dl[1];
    t2 += ch[0] + dh[0];
    t3 += ch[1] + dh[1];
  }
  for (; e < end; e += 4) {
    int sa = col[e];
    int ua = *(const int*)(h + (size_t)sa * 64 + q * 4);
    f32x2 al = __builtin_amdgcn_cvt_pk_f32_fp8(ua, false);
    f32x2 ah = __builtin_amdgcn_cvt_pk_f32_fp8(ua, true);
    s0 += al[0];
    s1 += al[1];
    s2 += ah[0];
    s3 += ah[1];
  }
  s0 += t0;
  s1 += t1;
  s2 += t2;
  s3 += t3;
  s0 += __shfl_xor(s0, 16);
  s1 += __shfl_xor(s1, 16);
  s2 += __shfl_xor(s2, 16);
  s3 += __shfl_xor(s3, 16);
  s0 += __shfl_xor(s0, 32);
  s1 += __shfl_xor(s1, 32);
  s2 += __shfl_xor(s2, 32);
  s3 += __shfl_xor(s3, 32);
}

// ---------------------------------------------------------------------------
// Fused agg + bias + ReLU + (row @ W) -> fp8. Block = 16 nodes, 4 waves.
// ---------------------------------------------------------------------------
__global__ __launch_bounds__(256) void agg_gemm_kernel(
    const unsigned char* __restrict__ h, const int* __restrict__ row_ptr,
    const int* __restrict__ col, const float* __restrict__ bias,
    const float* __restrict__ W, unsigned char* __restrict__ outg,
    int n_nodes) {
  __shared__ float rowbuf[16][68];
  int wid = threadIdx.x >> 6;
  int lane = threadIdx.x & 63;
  int slot = lane >> 4;
  int q = lane & 15;
  int nbase = blockIdx.x * 16;

#pragma unroll
  for (int n = 0; n < 4; ++n) {
    int ln = wid * 4 + n;
    int node = nbase + ln;
    float s0, s1, s2, s3;
    agg_node(h, col, row_ptr[node], row_ptr[node + 1], slot, q, s0, s1, s2, s3);
    if (lane < 16) {
      f32x4 r;
      r[0] = fmaxf(s0 + bias[q * 4 + 0], 0.f);
      r[1] = fmaxf(s1 + bias[q * 4 + 1], 0.f);
      r[2] = fmaxf(s2 + bias[q * 4 + 2], 0.f);
      r[3] = fmaxf(s3 + bias[q * 4 + 3], 0.f);
      *(f32x4*)&rowbuf[ln][q * 4] = r;
    }
  }
  __syncthreads();

  int lrow = lane & 15;
  int lk = (lane >> 4) * 8;
  f32x4 acc = {};
#pragma unroll
  for (int ks = 0; ks < 2; ++ks) {
    short8 a, bv;
#pragma unroll
    for (int j = 0; j < 8; ++j) a[j] = f2bf(rowbuf[lrow][ks * 32 + lk + j]);
#pragma unroll
    for (int j = 0; j < 8; ++j)
      bv[j] = f2bf(W[(size_t)(ks * 32 + lk + j) * 64 + wid * 16 + lrow]);
    acc = __builtin_amdgcn_mfma_f32_16x16x32_bf16(a, bv, acc, 0, 0, 0);
  }
  int crow = (lane >> 4) * 4;
#pragma unroll
  for (int r = 0; r < 4; ++r)
    outg[(size_t)(nbase + crow + r) * 64 + wid * 16 + lrow] =
        f32_to_fp8_hw(acc[r]);
}

// ---------------------------------------------------------------------------
// Final agg + bias + ReLU (fp32 out). Wave per node.
// ---------------------------------------------------------------------------
__global__ __launch_bounds__(256) void agg_final_kernel(
    const unsigned char* __restrict__ h, const int* __restrict__ row_ptr,
    const int* __restrict__ col, const float* __restrict__ bias,
    float* __restrict__ out, int n_nodes) {
  int node = blockIdx.x * 4 + (threadIdx.x >> 6);
  if (node >= n_nodes) return;
  int lane = threadIdx.x & 63;
  int slot = lane >> 4;
  int q = lane & 15;
  float s0, s1, s2, s3;
  agg_node(h, col, row_ptr[node], row_ptr[node + 1], slot, q, s0, s1, s2, s3);
  if (lane < 16) {
    float4 v;
    v.x = fmaxf(s0 + bias[q * 4 + 0], 0.f);
    v.y = fmaxf(s1 + bias[q * 4 + 1], 0.f);
    v.z = fmaxf(s2 + bias[q * 4 + 2], 0.f);
    v.w = fmaxf(s3 + bias[q * 4 + 3], 0.f);
    ((float4*)out)[(size_t)node * 16 + q] = v;
  }
}

extern "C" void kernel_launch(void* const* d_in, const int* in_sizes, int n_in,
                              void* d_out, int out_size, void* d_ws,
                              size_t ws_size, hipStream_t stream) {
  const float* x = (const float*)d_in[0];
  const int* src = (const int*)d_in[1];
  const int* dst = (const int*)d_in[2];
  const float* W1 = (const float*)d_in[3];
  const float* b1 = (const float*)d_in[4];
  const float* W2 = (const float*)d_in[5];
  const float* b2 = (const float*)d_in[6];
  const float* W3 = (const float*)d_in[7];
  const float* b3 = (const float*)d_in[8];
  float* out = (float*)d_out;

  const int N = N_NODES_C;
  const int E = N_EDGES_C;

  // Workspace layout (31 MB), as round 12.
  char* ws = (char*)d_ws;
  int* countsT = (int*)(ws + 0);
  int* btot = (int*)(ws + (1u << 20));
  int* bstart = (int*)(ws + (1u << 20) + (16u << 10));
  int* row_ptr = (int*)(ws + (2u << 20));
  unsigned* packed = (unsigned*)(ws + (3u << 20));
  int* col = (int*)(ws + (10u << 20));
  unsigned char* hA = (unsigned char*)(ws + (17u << 20));
  unsigned char* hB = (unsigned char*)(ws + (24u << 20));

  const int gemm_grid = (N + 63) / 64;  // 1563
  const int k1_grid = (NB_BUCK + 3) / 4;
  const int aggg_grid = N / 16;         // 6250
  const int aggf_grid = (N + 3) / 4;    // 25000

  // ---- CSR build; gemm1 overlapped with partition ----
  hist_kernel<<<NCHUNK, 256, 0, stream>>>(dst, countsT);
  scan_buckets_kernel<<<k1_grid, 256, 0, stream>>>(countsT, btot);
  scan_btot_kernel<<<1, 1024, 0, stream>>>(btot, bstart);
  part_gemm1_kernel<<<NPART + gemm_grid, 256, 0, stream>>>(
      src, dst, countsT, bstart, packed, x, W1, hA, N);
  sort_bucket_kernel<<<NB_BUCK, 256, 0, stream>>>(packed, bstart, col, row_ptr,
                                                  N, E);

  // ---- Layer 1 agg fused with gemm2: hB = fp8(relu(agg(hA)+b1) @ W2) ----
  agg_gemm_kernel<<<aggg_grid, 256, 0, stream>>>(hA, row_ptr, col, b1, W2, hB,
                                                 N);
  // ---- Layer 2 agg fused with gemm3: hA = fp8(relu(agg(hB)+b2) @ W3) ----
  agg_gemm_kernel<<<aggg_grid, 256, 0, stream>>>(hB, row_ptr, col, b2, W3, hA,
                                                 N);
  // ---- Layer 3 final: out = relu(agg(hA)+b3) (fp32) ----
  agg_final_kernel<<<aggf_grid, 256, 0, stream>>>(hA, row_ptr, col, b3, out, N);
}